// Round 10
// baseline (209.035 us; speedup 1.0000x reference)
//
#include <hip/hip_runtime.h>
#include <hip/hip_bf16.h>
#include <math.h>

typedef unsigned int  uint;
typedef unsigned short ushort;

// Problem constants
#define DD    256      // embedding dim
#define KK    2048     // num codewords
#define HW    1024     // H*W
#define NN    32768    // rows
#define NUMEL 8388608  // total elements
#define STRIDEB (DD*HW)

// Workspace layout (bytes) — peak 2.64 MB (bpart deleted vs R9)
#define WS_H2     0         // 2048 f32: 0.5*||e_k||^2
#define WS_COUNTS 8192      // 2048 i32
#define WS_EBF    16512     // emb frag-ordered bf16 hi/lo: 2 MB
#define WS_PV     2113664   // 65536 f32: per-half d^2 = xs2 + 2*bv
#define WS_PI     2375808   // 65536 i32 partial best index

// Output layout (floats): quantized_st | loss | perplexity | indices(as float)
#define OUT_LOSS  8388608
#define OUT_PPL   8388609
#define OUT_IDX   8388610

typedef __attribute__((ext_vector_type(8))) short  short8;   // 8 bf16 (4 VGPR)
typedef __attribute__((ext_vector_type(4))) float  float4v;  // 4 fp32 acc

typedef __attribute__((address_space(1))) uint guint;  // global
typedef __attribute__((address_space(3))) uint luint;  // LDS

__device__ __forceinline__ ushort f2bf(float f) {   // RNE fp32->bf16 bits
    uint u = __float_as_uint(f);
    return (ushort)((u + 0x7FFFu + ((u >> 16) & 1u)) >> 16);
}

// --------------------------------------------------------------------------
// Kernel 1: reorder emb (D,K) fp32 into MFMA-B-fragment-major bf16 hi/lo,
// AND accumulate h2[k] = 0.5*sum_d emb[d][k]^2 (atomic over 32 partials/k;
// h2+counts zeroed by the preceding hipMemsetAsync).
__global__ __launch_bounds__(256) void prep_emb(const float* __restrict__ emb,
                                                ushort* __restrict__ ebf,
                                                float* __restrict__ h2) {
    int g  = blockIdx.x * 256 + threadIdx.x;
    int k  = g & (KK - 1);
    int dg = g >> 11;          // 0..31
    int d0 = dg * 8;
    int s    = dg >> 2;
    int quad = dg & 3;
    int ct   = k >> 4;
    int l    = quad * 16 + (k & 15);

    union { ushort us[8]; uint4 v; } hu, lu;
    float p2 = 0.f;
#pragma unroll
    for (int j = 0; j < 8; ++j) {
        float v = emb[(size_t)(d0 + j) * KK + k];
        p2 += v * v;
        ushort hb = f2bf(v);
        float  hf = __uint_as_float(((uint)hb) << 16);
        hu.us[j] = hb;
        lu.us[j] = f2bf(v - hf);
    }
    size_t hi_off = (size_t)(((ct * 8 + s) * 2 + 0) * 64 + l) * 8;
    size_t lo_off = (size_t)(((ct * 8 + s) * 2 + 1) * 64 + l) * 8;
    *(uint4*)(ebf + hi_off) = hu.v;
    *(uint4*)(ebf + lo_off) = lu.v;
    atomicAdd(&h2[k], 0.5f * p2);
}

// --------------------------------------------------------------------------
// Kernel 2: split-bf16 MFMA distance + per-row argmin over a column half.
// Structure = verified v2 (108.4 us, best of 7 schedule variants — see R8
// ledger; do not re-iterate the schedule without asm-level evidence).
// R9 addition: accumulate xs2 = sum_d x^2 (fp32, in the A-build, hidden
// under load latency) and write pv = xs2 + 2*bv = per-half SQUARED
// DISTANCE. This lets the loss be computed from pv alone — quant no longer
// re-reads x (33.5 MB) and the bpart reduction machinery is deleted.
// Merge semantics: both halves shift by the same per-row xs2 -> winner and
// tie behavior unchanged (gaps >> fp32 ulp, evidenced by absmax stability).
__global__ __launch_bounds__(256, 2) void argmin_mfma(
    const float*  __restrict__ x,
    const ushort* __restrict__ ebf,
    const float*  __restrict__ h2,
    float* __restrict__ pv,
    int*   __restrict__ pi)
{
    __shared__ ushort sB[2][8192];   // 2 x 16 KB tile double-buffer
    __shared__ float  sH2[1024];     // 4 KB: h2 for this column half

    const int tid  = threadIdx.x;
    const int w    = tid >> 6;
    const int lane = tid & 63;
    const int m    = lane & 15;
    const int quad = lane >> 4;

    const int rb = blockIdx.x >> 1;
    const int ch = blockIdx.x & 1;
    const int n0 = rb * 128 + w * 32;          // wave's first row
    const int b  = n0 >> 10;
    const int hwb = n0 & 1023;
    const float* xb = x + (size_t)b * STRIDEB;
    const int cbase = ch * 1024;
    const int ctg0  = cbase >> 4;

    auto stage = [&](ushort* dst, int ctg) {
        const char* gs = (const char*)(ebf + (size_t)ctg * 8192) + tid * 16;
        char*       ls = (char*)dst + tid * 16;
#pragma unroll
        for (int i = 0; i < 4; ++i)
            __builtin_amdgcn_global_load_lds((guint*)(gs + i * 4096),
                                             (luint*)(ls + i * 4096),
                                             16, 0, 0);
    };

    stage(sB[0], ctg0);
    ((float4*)sH2)[tid] = ((const float4*)(h2 + cbase))[tid];

    // A fragments in registers: 2 strips x 8 slices x (hi,lo) + xs2 accum.
    short8 xh[2][8], xl[2][8];
    float xs2[2] = {0.f, 0.f};   // per-thread sum of x^2 over its 64 d's
#pragma unroll
    for (int st = 0; st < 2; ++st) {
        const int hw = hwb + st * 16 + m;
#pragma unroll
        for (int s = 0; s < 8; ++s) {
            const float* p = xb + (size_t)(s * 32 + quad * 8) * HW + hw;
            short8 hh, ll;
#pragma unroll
            for (int j = 0; j < 8; ++j) {
                float v = p[(size_t)j * HW];
                v = fminf(fmaxf(v, -10.f), 10.f);
                xs2[st] += v * v;
                ushort hb = f2bf(v);
                float  hf = __uint_as_float(((uint)hb) << 16);
                hh[j] = (short)hb;
                ll[j] = (short)f2bf(v - hf);
            }
            xh[st][s] = hh;
            xl[st][s] = ll;
        }
    }
    // Fold xs2 over the 4 quad-lanes: every lane then holds the full
    // 256-d sum for row (n0 + st*16 + m).
#pragma unroll
    for (int st = 0; st < 2; ++st) {
        xs2[st] += __shfl_xor(xs2[st], 16, 64);
        xs2[st] += __shfl_xor(xs2[st], 32, 64);
    }

    float bv[2][4] = {{1e30f,1e30f,1e30f,1e30f},{1e30f,1e30f,1e30f,1e30f}};
    int   bi[2][4] = {{0,0,0,0},{0,0,0,0}};

    auto compute_tile = [&](const ushort* sbc, int ct) {
        float4v ahh0 = {0,0,0,0}, ahl0 = {0,0,0,0}, alh0 = {0,0,0,0};
        float4v ahh1 = {0,0,0,0}, ahl1 = {0,0,0,0}, alh1 = {0,0,0,0};
#pragma unroll
        for (int s = 0; s < 8; ++s) {
            short8 eh = *(const short8*)&sbc[(s * 2 + 0) * 512 + lane * 8];
            short8 el = *(const short8*)&sbc[(s * 2 + 1) * 512 + lane * 8];
            alh0 = __builtin_amdgcn_mfma_f32_16x16x32_bf16(xl[0][s], eh, alh0, 0, 0, 0);
            ahl0 = __builtin_amdgcn_mfma_f32_16x16x32_bf16(xh[0][s], el, ahl0, 0, 0, 0);
            ahh0 = __builtin_amdgcn_mfma_f32_16x16x32_bf16(xh[0][s], eh, ahh0, 0, 0, 0);
            alh1 = __builtin_amdgcn_mfma_f32_16x16x32_bf16(xl[1][s], eh, alh1, 0, 0, 0);
            ahl1 = __builtin_amdgcn_mfma_f32_16x16x32_bf16(xh[1][s], el, ahl1, 0, 0, 0);
            ahh1 = __builtin_amdgcn_mfma_f32_16x16x32_bf16(xh[1][s], eh, ahh1, 0, 0, 0);
        }
        const int c  = cbase + ct * 16 + m;
        const float hv = sH2[ct * 16 + m];
#pragma unroll
        for (int i = 0; i < 4; ++i) {
            float s0 = hv - (ahh0[i] + (ahl0[i] + alh0[i]));
            float s1 = hv - (ahh1[i] + (ahl1[i] + alh1[i]));
            if (s0 < bv[0][i]) { bv[0][i] = s0; bi[0][i] = c; }
            if (s1 < bv[1][i]) { bv[1][i] = s1; bi[1][i] = c; }
        }
    };

    __syncthreads();   // drains tile-0 DMA (vmcnt) + sH2 write (lgkmcnt)

    for (int ct = 0; ct < 64; ct += 2) {
        stage(sB[1], ctg0 + ct + 1);
        compute_tile(sB[0], ct);
        __syncthreads();
        stage(sB[0], (ct + 2 < 64) ? (ctg0 + ct + 2) : ctg0);
        compute_tile(sB[1], ct + 1);
        __syncthreads();
    }

#pragma unroll
    for (int st = 0; st < 2; ++st) {
#pragma unroll
        for (int i = 0; i < 4; ++i) {
            float v  = bv[st][i];
            int   ix = bi[st][i];
#pragma unroll
            for (int msk = 8; msk >= 1; msk >>= 1) {
                float ov = __shfl_xor(v, msk, 64);
                int   oi = __shfl_xor(ix, msk, 64);
                if (ov < v || (ov == v && oi < ix)) { v = ov; ix = oi; }
            }
            // Row of this (quad,i) slot is quad*4+i; its xs2 lives on the
            // lane with m == quad*4+i (any quad) -> width-16 broadcast.
            float xr = __shfl(xs2[st], quad * 4 + i, 16);
            if (m == 0) {
                int n = n0 + st * 16 + quad * 4 + i;
                pv[n * 2 + ch] = xr + 2.0f * v;   // per-half squared distance
                pi[n * 2 + ch] = ix;
            }
        }
    }
}

// --------------------------------------------------------------------------
// Kernel 3: merge + gather + outq write + histogram. NO x read, NO MSE
// (loss now lives in pv). Block = (b, d-pair): stages 2 emb rows (16 KB)
// coalesced into LDS, merges its 1024 rows ONCE into sIdx, then gathers
// from LDS (scatter hits LDS, not VMEM). Write-bound: 33.5 MB outq.
__global__ __launch_bounds__(256) void quant_kernel(
    const float* __restrict__ emb,
    const float* __restrict__ pv,
    const int*   __restrict__ pi,
    float* __restrict__ out_idx_f,
    int*   __restrict__ counts,
    float* __restrict__ outq)
{
    __shared__ float sE[4096];    // emb rows d0, d0+1 (16 KB)
    __shared__ int   sIdx[1024];  // merged index per row of this b

    const int tid  = threadIdx.x;
    const int bidx = blockIdx.x;
    const int b    = bidx >> 7;        // 0..31
    const int dp   = bidx & 127;       // d-pair 0..127
    const int d0   = dp * 2;
    const int nbase = b * HW;

    // Stage 2 contiguous emb rows: 4096 floats, 4 x float4 per thread.
    {
        const float4* src = (const float4*)(emb + (size_t)d0 * KK);
        float4* dst = (float4*)sE;
#pragma unroll
        for (int i = 0; i < 4; ++i) dst[tid + i * 256] = src[tid + i * 256];
    }
    // Merge the two column halves for 4 rows/thread (strict <, half-0 on
    // ties — identical semantics to the R9 merge).
    {
        const int n = nbase + tid * 4;
        const float4* pv4 = (const float4*)(pv + (size_t)n * 2);
        const int4*   pi4 = (const int4*)(pi + (size_t)n * 2);
        float4 pva = pv4[0], pvb = pv4[1];
        int4   pia = pi4[0], pib = pi4[1];
        int i0 = (pva.y < pva.x) ? pia.y : pia.x;
        int i1 = (pva.w < pva.z) ? pia.w : pia.z;
        int i2 = (pvb.y < pvb.x) ? pib.y : pib.x;
        int i3 = (pvb.w < pvb.z) ? pib.w : pib.z;
        i0 = min(max(i0, 0), KK - 1); i1 = min(max(i1, 0), KK - 1);
        i2 = min(max(i2, 0), KK - 1); i3 = min(max(i3, 0), KK - 1);
        sIdx[tid * 4 + 0] = i0; sIdx[tid * 4 + 1] = i1;
        sIdx[tid * 4 + 2] = i2; sIdx[tid * 4 + 3] = i3;
        if (d0 == 0) {   // one writer per n: emit index + histogram
            float4 ixf = { (float)i0, (float)i1, (float)i2, (float)i3 };
            *(float4*)(out_idx_f + n) = ixf;
            atomicAdd(&counts[i0], 1);
            atomicAdd(&counts[i1], 1);
            atomicAdd(&counts[i2], 1);
            atomicAdd(&counts[i3], 1);
        }
    }
    __syncthreads();

    // Gather 8 elements (fixed d, consecutive hw) from LDS; 2 float4 stores.
    {
        const int e   = tid * 8;          // 0..2047 within block span
        const int dl  = e >> 10;          // 0 or 1
        const int hw0 = e & 1023;
        const float* row = sE + dl * 2048;
        float q[8];
#pragma unroll
        for (int j = 0; j < 8; ++j) q[j] = row[sIdx[hw0 + j]];
        float4 q0 = { q[0], q[1], q[2], q[3] };
        float4 q1 = { q[4], q[5], q[6], q[7] };
        float* dst = outq + (size_t)bidx * 2048 + e;
        *(float4*)(dst + 0) = q0;
        *(float4*)(dst + 4) = q1;
    }
}

// --------------------------------------------------------------------------
// Kernel 4: perplexity from histogram + loss from per-row squared
// distances (pv holds xs2 + 2*bv per half; min over halves = d^2_n).
__global__ __launch_bounds__(1024) void finalize_kernel(
    const int* __restrict__ counts,
    const float* __restrict__ pv,
    float* __restrict__ out)
{
    __shared__ float redp[16], redl[16];
    int tid = threadIdx.x;
    float s = 0.f;
#pragma unroll
    for (int k = tid; k < KK; k += 1024) {
        float p = (float)counts[k] * (1.0f / (float)NN);
        s += p * logf(p + 1e-10f);
    }
    float ls = 0.f;
    for (int n = tid; n < NN; n += 1024) {
        float2 pp = *(const float2*)(pv + (size_t)n * 2);
        ls += fminf(pp.x, pp.y);
    }
#pragma unroll
    for (int off = 32; off > 0; off >>= 1) {
        s  += __shfl_down(s, off, 64);
        ls += __shfl_down(ls, off, 64);
    }
    if ((tid & 63) == 0) { redp[tid >> 6] = s; redl[tid >> 6] = ls; }
    __syncthreads();
    if (tid == 0) {
        float tot = 0.f, lsum = 0.f;
#pragma unroll
        for (int i = 0; i < 16; ++i) { tot += redp[i]; lsum += redl[i]; }
        out[OUT_PPL]  = expf(-tot);
        out[OUT_LOSS] = lsum * 1.25f / (float)NUMEL;
    }
}

// --------------------------------------------------------------------------
extern "C" void kernel_launch(void* const* d_in, const int* in_sizes, int n_in,
                              void* d_out, int out_size, void* d_ws, size_t ws_size,
                              hipStream_t stream) {
    const float* x   = (const float*)d_in[0];
    const float* emb = (const float*)d_in[1];
    float* out = (float*)d_out;
    char*  ws  = (char*)d_ws;

    float*  h2     = (float*)(ws + WS_H2);
    int*    counts = (int*)(ws + WS_COUNTS);
    ushort* ebf    = (ushort*)(ws + WS_EBF);
    float*  pv     = (float*)(ws + WS_PV);
    int*    pi     = (int*)(ws + WS_PI);

    hipMemsetAsync(ws, 0, 16384, stream);   // h2 + counts
    prep_emb<<<256, 256, 0, stream>>>(emb, ebf, h2);
    argmin_mfma<<<512, 256, 0, stream>>>(x, ebf, h2, pv, pi);
    quant_kernel<<<4096, 256, 0, stream>>>(emb, pv, pi,
                                           out + OUT_IDX, counts, out);
    finalize_kernel<<<1, 1024, 0, stream>>>(counts, pv, out);
}